// Round 7
// baseline (447.417 us; speedup 1.0000x reference)
//
#include <hip/hip_runtime.h>

// DropBlock on (B,C,H,W)=(64,256,56,56), block_size=7, drop_prob=0.1
// mask_u is (B,C,50,50); gamma = 0.1/49 * 56^2/50^2.

#define BB 64
#define CC 256
#define HH 56
#define WW 56
#define HMM 50
#define WMM 50
#define BS 7

static constexpr unsigned int NPLANE = BB * CC;            // 16384
static constexpr unsigned int NTOT   = BB * CC * HH * WW;  // 51380224
static constexpr unsigned int NV     = NTOT / 4;           // 12845056 float4s
static constexpr unsigned int PLANEF = HMM * WMM;          // 2500 floats/plane
static constexpr unsigned int PLANE4 = PLANEF / 4;         // 625 float4/plane
static constexpr unsigned int AGRID  = 1024;               // apply blocks
static constexpr unsigned int PPB    = NPLANE / AGRID;     // 16 planes/block
static constexpr unsigned int F4PP   = HH * WW / 4;        // 784 float4/plane
static constexpr unsigned int F4PB   = PPB * F4PP;         // 12544 float4/block
static constexpr unsigned int KITER  = F4PB / 256;         // 49 float4/thread

typedef float f32x4 __attribute__((ext_vector_type(4)));

// 4 planes per 256-thread block. Phase 1: stage 4 planes (40 KB) into LDS via
// fully-coalesced float4 loads. Phase 2 (per wave, from LDS): ballot -> 50-bit
// row mask, horizontal dilation by shifts, vertical dilation by 3 shfl_up
// rounds. No global atomics. (Byte-identical to R4 — frozen this round.)
__global__ void __launch_bounds__(256) dropblock_mask_kernel(
    const float* __restrict__ mask_u,
    unsigned long long* __restrict__ rowmask,
    unsigned int* __restrict__ plane_cnt,
    float gamma)
{
    const unsigned int tid   = threadIdx.x;
    const unsigned int wid   = tid >> 6;
    const unsigned int lane  = tid & 63u;
    const unsigned int plane = blockIdx.x * 4u + wid;

    __shared__ float4 lds4[4 * PLANE4];  // 40 KB: 4 planes of raw mask_u
    const float* lds = reinterpret_cast<const float*>(lds4);

    // Phase 1: block-cooperative staging, 16 B/lane coalesced stream.
    {
        const float4* src = reinterpret_cast<const float4*>(mask_u)
                          + (size_t)blockIdx.x * (4 * PLANE4);
        #pragma unroll
        for (unsigned int r = 0; r < 10; ++r) {
            unsigned int idx = tid + r * 256u;
            if (idx < 4 * PLANE4) lds4[idx] = src[idx];
        }
    }
    __syncthreads();

    // Phase 2: per-wave ballot out of LDS (lanes 0..49 read consecutive words
    // of row i: <=2 lanes/bank aliasing, conflict-free).
    const float* mu = lds + wid * PLANEF;
    unsigned long long my_d = 0ull;  // lane i holds horizontally-dilated row i

    #pragma unroll
    for (int i = 0; i < HMM; ++i) {
        float v = (lane < WMM) ? mu[i * WMM + lane] : 1.0f;  // 1.0 >= gamma -> bit 0
        unsigned long long m = __ballot(v < gamma);
        // horizontal dilation: OR of shifts 0..6
        unsigned long long d = m | (m << 1);  // {0,1}
        d |= d << 2;                          // {0..3}
        d |= d << 3;                          // {0..6}
        if (lane == (unsigned)i) my_d = d;
    }

    // vertical dilation: lane i needs OR of rows [i-6, i] (lanes >= 50 hold 0,
    // so rows 50..55 correctly get only the tail window; shfl_up for lane<delta
    // returns own value, which is idempotent under OR)
    unsigned long long blocked = my_d;
    blocked |= __shfl_up(blocked, 1, 64);  // window {0,1}
    blocked |= __shfl_up(blocked, 2, 64);  // window {0..3}
    blocked |= __shfl_up(blocked, 3, 64);  // window {0..6}

    if (lane < HH) rowmask[plane * HH + lane] = blocked;

    // dropped-pixel count for this plane (lanes >= 56 have blocked==0)
    unsigned int cnt = __popcll(blocked);
    #pragma unroll
    for (int off = 32; off > 0; off >>= 1)
        cnt += __shfl_down(cnt, off, 64);
    if (lane == 0) plane_cnt[plane] = cnt;
}

// Single-block reduction of the 16384 per-plane counts -> scale factor.
// (Byte-identical to R4.)
__global__ void __launch_bounds__(1024) dropblock_scale_kernel(
    const unsigned int* __restrict__ plane_cnt,
    float* __restrict__ scale_out)
{
    __shared__ unsigned int ssum[16];
    const unsigned int t = threadIdx.x;

    const uint4* pc4 = reinterpret_cast<const uint4*>(plane_cnt);  // 4096 uint4
    uint4 a = pc4[t];
    uint4 b = pc4[t + 1024];
    uint4 c = pc4[t + 2048];
    uint4 d = pc4[t + 3072];
    unsigned int s = a.x + a.y + a.z + a.w
                   + b.x + b.y + b.z + b.w
                   + c.x + c.y + c.z + c.w
                   + d.x + d.y + d.z + d.w;

    #pragma unroll
    for (int off = 32; off > 0; off >>= 1)
        s += __shfl_down(s, off, 64);
    if ((t & 63u) == 0u) ssum[t >> 6] = s;
    __syncthreads();

    if (t < 16) {
        unsigned int v = ssum[t];
        #pragma unroll
        for (int off = 8; off > 0; off >>= 1)
            v += __shfl_down(v, off, 64);
        if (t == 0) {
            // NTOT exactly representable in fp32; kept-count rounding error
            // <= 2 ulp -> scale rel err ~1e-7, way under threshold.
            *scale_out = (float)NTOT / (float)(NTOT - v);
        }
    }
}

// Apply: each block owns 16 whole planes (12544 contiguous float4).
// Stage the block's 896 rowmask words into LDS once (kills 49 scattered
// global rowmask loads/thread), then 49 block-strided float4 iterations:
// every load/store instruction is a contiguous 1KB wave segment (R5 showed
// per-thread ADJACENT pairs fragment coalescing - this form keeps segments
// whole), and unroll-7 puts 7 float4 (112B) per thread in flight to cover
// HBM latency (1 float4 = 16B/thread in flight capped us at 3.9 TB/s).
__global__ void __launch_bounds__(256) dropblock_apply_kernel(
    const float* __restrict__ x,
    const unsigned long long* __restrict__ rowmask,
    const float* __restrict__ scale_ptr,
    float* __restrict__ out)
{
    const unsigned int tid = threadIdx.x;
    const unsigned int b   = blockIdx.x;

    __shared__ unsigned long long rsh[PPB * HH];  // 896 u64 = 7168 B

    // stage this block's rowmasks, coalesced 8B/lane
    const unsigned long long* rsrc = rowmask + (size_t)b * (PPB * HH);
    #pragma unroll
    for (unsigned int r = 0; r < 4; ++r) {
        unsigned int i = tid + r * 256u;
        if (i < PPB * HH) rsh[i] = rsrc[i];
    }
    const float scale = *scale_ptr;  // uniform, precomputed
    __syncthreads();

    const f32x4* xp = reinterpret_cast<const f32x4*>(x)  + (size_t)b * F4PB;
    f32x4*       op = reinterpret_cast<f32x4*>(out)      + (size_t)b * F4PB;

    #pragma unroll 7
    for (unsigned int k = 0; k < KITER; ++k) {
        unsigned int il  = tid + k * 256u;          // [0, 12544)
        unsigned int pl  = il / F4PP;               // /784 -> plane-local
        unsigned int rem = il - pl * F4PP;
        unsigned int row = rem / 14u;
        unsigned int col = (rem - row * 14u) * 4u;

        unsigned long long rm = rsh[pl * HH + row];
        f32x4 xv = xp[il];
        f32x4 o;
        #pragma unroll
        for (int j = 0; j < 4; ++j)
            o[j] = ((rm >> (col + j)) & 1ull) ? 0.0f : xv[j] * scale;
        op[il] = o;
    }
}

extern "C" void kernel_launch(void* const* d_in, const int* in_sizes, int n_in,
                              void* d_out, int out_size, void* d_ws, size_t ws_size,
                              hipStream_t stream) {
    const float* x      = (const float*)d_in[0];
    const float* mask_u = (const float*)d_in[1];
    float* out          = (float*)d_out;

    // ws layout (everything fully overwritten each call -> re-poison safe):
    //   [0, 64)           : scale (float, own cache line)
    //   [64, 64+65536)    : per-plane drop counts (16384 u32)
    //   [65600, +7340032) : 16384 planes * 56 rows * uint64 row bitmasks
    float* scale_ws             = (float*)d_ws;
    unsigned int* plane_cnt     = (unsigned int*)((char*)d_ws + 64);
    unsigned long long* rowmask = (unsigned long long*)((char*)d_ws + 65600);

    // gamma computed in double then cast to fp32, matching JAX's weak-typed
    // promotion of the Python float in (mask_u < gamma).
    const double gd = 0.1 / ((double)BS * BS) * ((double)HH * HH) /
                      (((double)HH - BS + 1.0) * ((double)HH - BS + 1.0));
    const float gamma = (float)gd;

    dropblock_mask_kernel<<<NPLANE / 4, 256, 0, stream>>>(
        mask_u, rowmask, plane_cnt, gamma);

    dropblock_scale_kernel<<<1, 1024, 0, stream>>>(plane_cnt, scale_ws);

    dropblock_apply_kernel<<<AGRID, 256, 0, stream>>>(
        x, rowmask, scale_ws, out);
}

// Round 8
// 440.506 us; speedup vs baseline: 1.0157x; 1.0157x over previous
//
#include <hip/hip_runtime.h>

// DropBlock on (B,C,H,W)=(64,256,56,56), block_size=7, drop_prob=0.1
// mask_u is (B,C,50,50); gamma = 0.1/49 * 56^2/50^2.

#define BB 64
#define CC 256
#define HH 56
#define WW 56
#define HMM 50
#define WMM 50
#define BS 7

static constexpr unsigned int NPLANE  = BB * CC;            // 16384
static constexpr unsigned int NTOT    = BB * CC * HH * WW;  // 51380224
static constexpr unsigned int NV      = NTOT / 4;           // 12845056 float4s
static constexpr unsigned int PLANEF  = HMM * WMM;          // 2500 floats/plane
static constexpr unsigned int PLANE4  = PLANEF / 4;         // 625 float4/plane
static constexpr unsigned int MGRID   = 1024;               // mask blocks
static constexpr unsigned int MPPB    = 16;                 // planes per mask block
static constexpr unsigned int MROUNDS = 4;                  // rounds (4 planes each)
static constexpr unsigned int R4CNT   = 4 * PLANE4;         // 2500 float4/round

typedef float f32x4 __attribute__((ext_vector_type(4)));

// Pipelined mask kernel. Each 256-thread block owns 16 planes, processed as
// 4 rounds of 4 planes (one plane per wave). While round r is ballot-processed
// out of LDS, round r+1's 40KB is already in flight into registers (T14
// issue-early/write-late: reg-staging is required because ballot needs the
// lane=column layout, which global_load_lds can't scatter to). R4's version
// had a strict stage->barrier->process structure: with 4 blocks/CU, half the
// resident blocks had zero memory outstanding at any time, capping the
// 164 MB read stream at ~2.4 TB/s (68 us).
__global__ void __launch_bounds__(256) dropblock_mask_kernel(
    const float* __restrict__ mask_u,
    unsigned long long* __restrict__ rowmask,
    unsigned int* __restrict__ block_cnt,
    float gamma)
{
    const unsigned int tid  = threadIdx.x;
    const unsigned int wid  = tid >> 6;
    const unsigned int lane = tid & 63u;
    const unsigned int b    = blockIdx.x;

    __shared__ float4 lds4[R4CNT];   // 40 KB: 4 planes of raw mask_u
    __shared__ unsigned int csh[4];
    const float* lds = reinterpret_cast<const float*>(lds4);

    const float4* base = reinterpret_cast<const float4*>(mask_u)
                       + (size_t)b * (MPPB * PLANE4);

    // prologue: prefetch round 0 into registers (10 independent float4 loads)
    float4 pf[10];
    #pragma unroll
    for (unsigned int s = 0; s < 10; ++s) {
        unsigned int i = tid + s * 256u;
        pf[s] = (i < R4CNT) ? base[i] : make_float4(0.f, 0.f, 0.f, 0.f);
    }

    unsigned int wcnt = 0;  // per-wave dropped count (lane 0)

    for (unsigned int r = 0; r < MROUNDS; ++r) {
        // write the prefetched round into LDS (vmcnt wait lands here)
        #pragma unroll
        for (unsigned int s = 0; s < 10; ++s) {
            unsigned int i = tid + s * 256u;
            if (i < R4CNT) lds4[i] = pf[s];
        }
        __syncthreads();

        // issue next round's global loads NOW; they complete under the
        // ballot processing below and are consumed at the next ds_write
        if (r + 1 < MROUNDS) {
            const float4* src = base + (r + 1) * R4CNT;
            #pragma unroll
            for (unsigned int s = 0; s < 10; ++s) {
                unsigned int i = tid + s * 256u;
                pf[s] = (i < R4CNT) ? src[i] : make_float4(0.f, 0.f, 0.f, 0.f);
            }
        }

        // process: wave wid handles plane 4r+wid. Lanes 0..49 read consecutive
        // words of row i (<=2 lanes/bank, conflict-free); ballot -> 50-bit row
        // mask; horizontal dilation by shifts; vertical by 3 shfl_up rounds.
        const float* mu = lds + wid * PLANEF;
        unsigned long long my_d = 0ull;  // lane i: h-dilated row i
        #pragma unroll
        for (int i = 0; i < HMM; ++i) {
            float v = (lane < WMM) ? mu[i * WMM + lane] : 1.0f;  // 1.0>=gamma -> 0
            unsigned long long m = __ballot(v < gamma);
            unsigned long long d = m | (m << 1);  // shifts {0,1}
            d |= d << 2;                          // {0..3}
            d |= d << 3;                          // {0..6}
            if (lane == (unsigned)i) my_d = d;
        }
        // lanes >= 50 start at 0, so rows 50..55 get only the valid tail
        // window; shfl_up with lane<delta returns own value (OR-idempotent)
        unsigned long long blocked = my_d;
        blocked |= __shfl_up(blocked, 1, 64);
        blocked |= __shfl_up(blocked, 2, 64);
        blocked |= __shfl_up(blocked, 3, 64);

        const unsigned int plane = b * MPPB + r * 4u + wid;
        if (lane < HH) rowmask[plane * HH + lane] = blocked;

        unsigned int c = __popcll(blocked);  // lanes >= 56 have blocked==0
        #pragma unroll
        for (int off = 32; off > 0; off >>= 1)
            c += __shfl_down(c, off, 64);
        if (lane == 0) wcnt += c;

        __syncthreads();  // protect lds4 before next round's ds_write
    }

    if (lane == 0) csh[wid] = wcnt;
    __syncthreads();
    if (tid == 0) block_cnt[b] = csh[0] + csh[1] + csh[2] + csh[3];
}

// Single-block reduction of the 1024 per-block counts -> scale factor.
__global__ void __launch_bounds__(256) dropblock_scale_kernel(
    const unsigned int* __restrict__ block_cnt,
    float* __restrict__ scale_out)
{
    __shared__ unsigned int ssum[4];
    const unsigned int t = threadIdx.x;

    const uint4* c4 = reinterpret_cast<const uint4*>(block_cnt);  // 256 uint4
    uint4 v = c4[t];
    unsigned int s = v.x + v.y + v.z + v.w;
    #pragma unroll
    for (int off = 32; off > 0; off >>= 1)
        s += __shfl_down(s, off, 64);
    if ((t & 63u) == 0u) ssum[t >> 6] = s;
    __syncthreads();

    if (t == 0) {
        unsigned int tot = ssum[0] + ssum[1] + ssum[2] + ssum[3];
        // NTOT exactly representable in fp32; kept-count rounding error
        // <= 2 ulp -> scale rel err ~1e-7, way under threshold.
        *scale_out = (float)NTOT / (float)(NTOT - tot);
    }
}

// float4 over the whole tensor: out = x * (dropped ? 0 : scale)
// (Flat form — byte-identical to R4's apply, the best measured config.
// R2/R5/R7 variants all regressed; do not touch.)
__global__ void __launch_bounds__(256) dropblock_apply_kernel(
    const float* __restrict__ x,
    const unsigned long long* __restrict__ rowmask,
    const float* __restrict__ scale_ptr,
    float* __restrict__ out)
{
    unsigned int idx = blockIdx.x * 256u + threadIdx.x;
    if (idx >= NV) return;

    const float scale = *scale_ptr;  // uniform scalar load, precomputed

    // idx -> (plane, row, col) ; 784 float4s per plane, 14 per row
    unsigned int plane = idx / (HH * WW / 4);            // / 784
    unsigned int rem   = idx - plane * (HH * WW / 4);
    unsigned int row   = rem / (WW / 4);                 // / 14
    unsigned int colv  = rem - row * (WW / 4);
    unsigned int col   = colv * 4;

    unsigned long long rm = rowmask[plane * HH + row];
    float4 xv = reinterpret_cast<const float4*>(x)[idx];
    float4 o;
    o.x = ((rm >> (col + 0)) & 1ull) ? 0.0f : xv.x * scale;
    o.y = ((rm >> (col + 1)) & 1ull) ? 0.0f : xv.y * scale;
    o.z = ((rm >> (col + 2)) & 1ull) ? 0.0f : xv.z * scale;
    o.w = ((rm >> (col + 3)) & 1ull) ? 0.0f : xv.w * scale;
    reinterpret_cast<float4*>(out)[idx] = o;
}

extern "C" void kernel_launch(void* const* d_in, const int* in_sizes, int n_in,
                              void* d_out, int out_size, void* d_ws, size_t ws_size,
                              hipStream_t stream) {
    const float* x      = (const float*)d_in[0];
    const float* mask_u = (const float*)d_in[1];
    float* out          = (float*)d_out;

    // ws layout (everything fully overwritten each call -> re-poison safe):
    //   [0, 64)          : scale (float, own cache line)
    //   [64, 64+4096)    : per-block drop counts (1024 u32)
    //   [8192, +7340032) : 16384 planes * 56 rows * uint64 row bitmasks
    float* scale_ws             = (float*)d_ws;
    unsigned int* block_cnt     = (unsigned int*)((char*)d_ws + 64);
    unsigned long long* rowmask = (unsigned long long*)((char*)d_ws + 8192);

    // gamma computed in double then cast to fp32, matching JAX's weak-typed
    // promotion of the Python float in (mask_u < gamma).
    const double gd = 0.1 / ((double)BS * BS) * ((double)HH * HH) /
                      (((double)HH - BS + 1.0) * ((double)HH - BS + 1.0));
    const float gamma = (float)gd;

    dropblock_mask_kernel<<<MGRID, 256, 0, stream>>>(
        mask_u, rowmask, block_cnt, gamma);

    dropblock_scale_kernel<<<1, 256, 0, stream>>>(block_cnt, scale_ws);

    dropblock_apply_kernel<<<(NV + 255u) / 256u, 256, 0, stream>>>(
        x, rowmask, scale_ws, out);
}

// Round 9
// 434.025 us; speedup vs baseline: 1.0309x; 1.0149x over previous
//
#include <hip/hip_runtime.h>

// DropBlock on (B,C,H,W)=(64,256,56,56), block_size=7, drop_prob=0.1
// mask_u is (B,C,50,50); gamma = 0.1/49 * 56^2/50^2.

#define BB 64
#define CC 256
#define HH 56
#define WW 56
#define HMM 50
#define WMM 50
#define BS 7

static constexpr unsigned int NPLANE = BB * CC;            // 16384
static constexpr unsigned int NTOT   = BB * CC * HH * WW;  // 51380224
static constexpr unsigned int NV     = NTOT / 4;           // 12845056 float4s
static constexpr unsigned int PLANEF = HMM * WMM;          // 2500 floats/plane
static constexpr unsigned int PLANE4 = PLANEF / 4;         // 625 float4/plane

typedef float f32x4 __attribute__((ext_vector_type(4)));

// 2 planes per 256-thread block (was 4 in R4). LDS 20 KB -> 8 blocks/CU =
// 32 waves/CU (full occupancy), vs R4's 40 KB -> 4 blocks/CU = 50%.
// The stage->barrier->process structure leaves a block with zero memory
// outstanding during its ballot phase; doubling resident blocks doubles the
// probability that some block on the CU is streaming, raising effective
// staging BW. (R8's per-block reg-prefetch pipeline attacked the same gap
// and regressed; this is the occupancy-side attack.) Ballot work per CU is
// unchanged (total planes fixed). Waves 2-3 stage then exit; waves 0-1 each
// process one plane with the exact R4 ballot/shfl code.
__global__ void __launch_bounds__(256) dropblock_mask_kernel(
    const float* __restrict__ mask_u,
    unsigned long long* __restrict__ rowmask,
    unsigned int* __restrict__ plane_cnt,
    float gamma)
{
    const unsigned int tid   = threadIdx.x;
    const unsigned int wid   = tid >> 6;
    const unsigned int lane  = tid & 63u;

    __shared__ float4 lds4[2 * PLANE4];  // 20 KB: 2 planes of raw mask_u
    const float* lds = reinterpret_cast<const float*>(lds4);

    // Phase 1: block-cooperative staging, 16 B/lane coalesced stream.
    {
        const float4* src = reinterpret_cast<const float4*>(mask_u)
                          + (size_t)blockIdx.x * (2 * PLANE4);
        #pragma unroll
        for (unsigned int r = 0; r < 5; ++r) {
            unsigned int idx = tid + r * 256u;
            if (idx < 2 * PLANE4) lds4[idx] = src[idx];
        }
    }
    __syncthreads();

    if (wid >= 2) return;  // staging-only waves (exit after barrier)

    const unsigned int plane = blockIdx.x * 2u + wid;

    // Phase 2: per-wave ballot out of LDS (lanes 0..49 read consecutive words
    // of row i: <=2 lanes/bank aliasing, conflict-free).
    const float* mu = lds + wid * PLANEF;
    unsigned long long my_d = 0ull;  // lane i holds horizontally-dilated row i

    #pragma unroll
    for (int i = 0; i < HMM; ++i) {
        float v = (lane < WMM) ? mu[i * WMM + lane] : 1.0f;  // 1.0 >= gamma -> bit 0
        unsigned long long m = __ballot(v < gamma);
        // horizontal dilation: OR of shifts 0..6
        unsigned long long d = m | (m << 1);  // {0,1}
        d |= d << 2;                          // {0..3}
        d |= d << 3;                          // {0..6}
        if (lane == (unsigned)i) my_d = d;
    }

    // vertical dilation: lane i needs OR of rows [i-6, i] (lanes >= 50 hold 0,
    // so rows 50..55 correctly get only the tail window; shfl_up for lane<delta
    // returns own value, which is idempotent under OR)
    unsigned long long blocked = my_d;
    blocked |= __shfl_up(blocked, 1, 64);  // window {0,1}
    blocked |= __shfl_up(blocked, 2, 64);  // window {0..3}
    blocked |= __shfl_up(blocked, 3, 64);  // window {0..6}

    if (lane < HH) rowmask[plane * HH + lane] = blocked;

    // dropped-pixel count for this plane (lanes >= 56 have blocked==0)
    unsigned int cnt = __popcll(blocked);
    #pragma unroll
    for (int off = 32; off > 0; off >>= 1)
        cnt += __shfl_down(cnt, off, 64);
    if (lane == 0) plane_cnt[plane] = cnt;
}

// Single-block reduction of the 16384 per-plane counts -> scale factor.
// (Byte-identical to R4.)
__global__ void __launch_bounds__(1024) dropblock_scale_kernel(
    const unsigned int* __restrict__ plane_cnt,
    float* __restrict__ scale_out)
{
    __shared__ unsigned int ssum[16];
    const unsigned int t = threadIdx.x;

    const uint4* pc4 = reinterpret_cast<const uint4*>(plane_cnt);  // 4096 uint4
    uint4 a = pc4[t];
    uint4 b = pc4[t + 1024];
    uint4 c = pc4[t + 2048];
    uint4 d = pc4[t + 3072];
    unsigned int s = a.x + a.y + a.z + a.w
                   + b.x + b.y + b.z + b.w
                   + c.x + c.y + c.z + c.w
                   + d.x + d.y + d.z + d.w;

    #pragma unroll
    for (int off = 32; off > 0; off >>= 1)
        s += __shfl_down(s, off, 64);
    if ((t & 63u) == 0u) ssum[t >> 6] = s;
    __syncthreads();

    if (t < 16) {
        unsigned int v = ssum[t];
        #pragma unroll
        for (int off = 8; off > 0; off >>= 1)
            v += __shfl_down(v, off, 64);
        if (t == 0) {
            // NTOT exactly representable in fp32; kept-count rounding error
            // <= 2 ulp -> scale rel err ~1e-7, way under threshold.
            *scale_out = (float)NTOT / (float)(NTOT - v);
        }
    }
}

// float4 over the whole tensor: out = x * (dropped ? 0 : scale)
// (Flat form — byte-identical to R4's apply, the best measured config.
// R2/R5/R7 variants all regressed; do not touch.)
__global__ void __launch_bounds__(256) dropblock_apply_kernel(
    const float* __restrict__ x,
    const unsigned long long* __restrict__ rowmask,
    const float* __restrict__ scale_ptr,
    float* __restrict__ out)
{
    unsigned int idx = blockIdx.x * 256u + threadIdx.x;
    if (idx >= NV) return;

    const float scale = *scale_ptr;  // uniform scalar load, precomputed

    // idx -> (plane, row, col) ; 784 float4s per plane, 14 per row
    unsigned int plane = idx / (HH * WW / 4);            // / 784
    unsigned int rem   = idx - plane * (HH * WW / 4);
    unsigned int row   = rem / (WW / 4);                 // / 14
    unsigned int colv  = rem - row * (WW / 4);
    unsigned int col   = colv * 4;

    unsigned long long rm = rowmask[plane * HH + row];
    float4 xv = reinterpret_cast<const float4*>(x)[idx];
    float4 o;
    o.x = ((rm >> (col + 0)) & 1ull) ? 0.0f : xv.x * scale;
    o.y = ((rm >> (col + 1)) & 1ull) ? 0.0f : xv.y * scale;
    o.z = ((rm >> (col + 2)) & 1ull) ? 0.0f : xv.z * scale;
    o.w = ((rm >> (col + 3)) & 1ull) ? 0.0f : xv.w * scale;
    reinterpret_cast<float4*>(out)[idx] = o;
}

extern "C" void kernel_launch(void* const* d_in, const int* in_sizes, int n_in,
                              void* d_out, int out_size, void* d_ws, size_t ws_size,
                              hipStream_t stream) {
    const float* x      = (const float*)d_in[0];
    const float* mask_u = (const float*)d_in[1];
    float* out          = (float*)d_out;

    // ws layout (everything fully overwritten each call -> re-poison safe):
    //   [0, 64)           : scale (float, own cache line)
    //   [64, 64+65536)    : per-plane drop counts (16384 u32)
    //   [65600, +7340032) : 16384 planes * 56 rows * uint64 row bitmasks
    float* scale_ws             = (float*)d_ws;
    unsigned int* plane_cnt     = (unsigned int*)((char*)d_ws + 64);
    unsigned long long* rowmask = (unsigned long long*)((char*)d_ws + 65600);

    // gamma computed in double then cast to fp32, matching JAX's weak-typed
    // promotion of the Python float in (mask_u < gamma).
    const double gd = 0.1 / ((double)BS * BS) * ((double)HH * HH) /
                      (((double)HH - BS + 1.0) * ((double)HH - BS + 1.0));
    const float gamma = (float)gd;

    dropblock_mask_kernel<<<NPLANE / 2, 256, 0, stream>>>(
        mask_u, rowmask, plane_cnt, gamma);

    dropblock_scale_kernel<<<1, 1024, 0, stream>>>(plane_cnt, scale_ws);

    dropblock_apply_kernel<<<(NV + 255u) / 256u, 256, 0, stream>>>(
        x, rowmask, scale_ws, out);
}